// Round 1
// baseline (1419.570 us; speedup 1.0000x reference)
//
#include <hip/hip_runtime.h>
#include <math.h>

#define KS 5
#define NEGV (-1e30f)

// ---------- float <-> ordered-uint for atomic max ----------
__device__ __forceinline__ unsigned int flipf(float f) {
    unsigned int b = __float_as_uint(f);
    return b ^ ((b >> 31) ? 0xFFFFFFFFu : 0x80000000u);
}
__device__ __forceinline__ float unflipf(unsigned int u) {
    unsigned int b = u ^ ((u >> 31) ? 0x80000000u : 0xFFFFFFFFu);
    return __uint_as_float(b);
}

// ---------- spline conv: per-(edge, out-channel) thread, atomic scatter ----------
template<int FIN, int FOUT>
__global__ void conv_edges(const float* __restrict__ x,
                           const int* __restrict__ src,
                           const int* __restrict__ dst,
                           const float* __restrict__ pseudo,
                           const float* __restrict__ W,
                           float* __restrict__ agg,
                           float* __restrict__ deg,
                           int E)
{
    int stride = gridDim.x * blockDim.x;
    int total = E * FOUT;
    for (int t = blockIdx.x * blockDim.x + threadIdx.x; t < total; t += stride) {
        int e = t / FOUT;
        int o = t - e * FOUT;
        int s = src[e];
        int d = dst[e];
        // spline basis (degree-1, open, K=5 per dim)
        float f0, f1, f2; int b0, b1, b2;
        {
            float p = pseudo[e * 3 + 0];
            float v = fminf(fmaxf(p, 0.f), 1.f) * (float)(KS - 1);
            float fl = fminf(floorf(v), (float)(KS - 2));
            b0 = (int)fl; f0 = v - fl;
            p = pseudo[e * 3 + 1];
            v = fminf(fmaxf(p, 0.f), 1.f) * (float)(KS - 1);
            fl = fminf(floorf(v), (float)(KS - 2));
            b1 = (int)fl; f1 = v - fl;
            p = pseudo[e * 3 + 2];
            v = fminf(fmaxf(p, 0.f), 1.f) * (float)(KS - 1);
            fl = fminf(floorf(v), (float)(KS - 2));
            b2 = (int)fl; f2 = v - fl;
        }
        float acc = 0.f;
        #pragma unroll
        for (int c = 0; c < 8; ++c) {
            int c0 = c & 1, c1 = (c >> 1) & 1, c2 = (c >> 2) & 1;
            float bw = (c0 ? f0 : 1.f - f0) * (c1 ? f1 : 1.f - f1) * (c2 ? f2 : 1.f - f2);
            int k = (b0 + c0) + (b1 + c1) * KS + (b2 + c2) * KS * KS;
            const float* Wk = W + (size_t)k * FIN * FOUT + o;
            float a = 0.f;
            #pragma unroll
            for (int i = 0; i < FIN; ++i)
                a = fmaf(x[s * FIN + i], Wk[i * FOUT], a);
            acc = fmaf(bw, a, acc);
        }
        atomicAdd(&agg[(size_t)d * FOUT + o], acc);
        if (o == 0) atomicAdd(&deg[d], 1.0f);
    }
}

// ---------- finalize: mean + root weight + bias + activation ----------
template<int FIN, int FOUT, int ACT>  // ACT 0 = ELU, 1 = ReLU
__global__ void node_finalize(const float* __restrict__ x,
                              const float* __restrict__ agg,
                              const float* __restrict__ deg,
                              const float* __restrict__ root,
                              const float* __restrict__ bias,
                              float* __restrict__ out, int N)
{
    int stride = gridDim.x * blockDim.x;
    int total = N * FOUT;
    for (int t = blockIdx.x * blockDim.x + threadIdx.x; t < total; t += stride) {
        int n = t / FOUT;
        int o = t - n * FOUT;
        float a = agg[t] / fmaxf(deg[n], 1.f) + bias[o];
        #pragma unroll
        for (int i = 0; i < FIN; ++i)
            a = fmaf(x[n * FIN + i], root[i * FOUT + o], a);
        if (ACT == 0) a = (a > 0.f) ? a : expm1f(a);
        else          a = fmaxf(a, 0.f);
        out[t] = a;
    }
}

// ---------- pool init: seg-max and pooled buffers to flip(NEG) ----------
__global__ void pool_init(unsigned int* __restrict__ segw,
                          unsigned int* __restrict__ pooled, int C, int CF)
{
    int stride = gridDim.x * blockDim.x;
    unsigned int v = flipf(NEGV);
    for (int t = blockIdx.x * blockDim.x + threadIdx.x; t < C; t += stride) segw[t] = v;
    for (int t = blockIdx.x * blockDim.x + threadIdx.x; t < CF; t += stride) pooled[t] = v;
}

// ---------- attention weight + segment max ----------
template<int F>
__global__ void att_segmax(const float* __restrict__ x,
                           const float* __restrict__ attw,
                           const float* __restrict__ attb,
                           const int* __restrict__ cluster,
                           float* __restrict__ wout,
                           unsigned int* __restrict__ segw, int N)
{
    int stride = gridDim.x * blockDim.x;
    for (int n = blockIdx.x * blockDim.x + threadIdx.x; n < N; n += stride) {
        float w = attb[0];
        #pragma unroll
        for (int f = 0; f < F; ++f)
            w = fmaf(x[n * F + f], attw[2 * f], w);
        wout[n] = w;
        atomicMax(&segw[cluster[n]], flipf(w));
    }
}

// ---------- scatter feature max (winner-gated if WEIGHTED) ----------
template<int F, bool WEIGHTED>
__global__ void pool_scatter(const float* __restrict__ x,
                             const float* __restrict__ wout,
                             const unsigned int* __restrict__ segw,
                             const int* __restrict__ cluster,
                             unsigned int* __restrict__ pooled, int N)
{
    int stride = gridDim.x * blockDim.x;
    int total = N * F;
    for (int t = blockIdx.x * blockDim.x + threadIdx.x; t < total; t += stride) {
        int n = t / F;
        int f = t - n * F;
        int c = cluster[n];
        bool win = true;
        if (WEIGHTED) win = (wout[n] >= unflipf(segw[c]));
        if (win) atomicMax(&pooled[(size_t)c * F + f], flipf(x[t]));
    }
}

// ---------- unflip + zero empty clusters ----------
__global__ void pool_final(const unsigned int* __restrict__ pooled,
                           float* __restrict__ out, int total)
{
    int stride = gridDim.x * blockDim.x;
    for (int t = blockIdx.x * blockDim.x + threadIdx.x; t < total; t += stride) {
        float v = unflipf(pooled[t]);
        out[t] = (v <= NEGV * 0.5f) ? 0.f : v;
    }
}

// ---------- final FC + log_softmax: [128,64] -> [16,512] @ [512,10] ----------
__global__ void fc_logsoftmax(const float* __restrict__ h,
                              const float* __restrict__ fcw,
                              const float* __restrict__ fcb,
                              float* __restrict__ out)
{
    __shared__ float logits[16][10];
    __shared__ float lse[16];
    int t = threadIdx.x;
    if (t < 160) {
        int g = t / 10, cls = t - g * 10;
        float a = fcb[cls];
        for (int j = 0; j < 512; ++j)
            a = fmaf(h[g * 512 + j], fcw[j * 10 + cls], a);
        logits[g][cls] = a;
    }
    __syncthreads();
    if (t < 16) {
        float m = -1e30f;
        for (int c = 0; c < 10; ++c) m = fmaxf(m, logits[t][c]);
        float s = 0.f;
        for (int c = 0; c < 10; ++c) s += expf(logits[t][c] - m);
        lse[t] = m + logf(s);
    }
    __syncthreads();
    if (t < 160) out[t] = logits[t / 10][t - (t / 10) * 10] - lse[t / 10];
}

// ---------- host orchestration ----------
static inline int igrid(long long total, int block, int cap = 8192) {
    long long g = (total + block - 1) / block;
    if (g > cap) g = cap;
    if (g < 1) g = 1;
    return (int)g;
}

template<int FIN, int FOUT, int ACT, bool WEIGHTED>
static void run_layer(const float* xin,
                      const int* src, const int* dst, const float* ps,
                      const float* W, const float* root, const float* bias,
                      const float* attw, const float* attb, const int* cluster,
                      int N, int E, int C,
                      float* agg, float* deg, float* wbuf,
                      unsigned int* segw, unsigned int* pooled,
                      float* hconv, float* hpool, hipStream_t stream)
{
    hipMemsetAsync(agg, 0, (size_t)N * FOUT * sizeof(float), stream);
    hipMemsetAsync(deg, 0, (size_t)N * sizeof(float), stream);
    conv_edges<FIN, FOUT><<<igrid((long long)E * FOUT, 256), 256, 0, stream>>>(
        xin, src, dst, ps, W, agg, deg, E);
    node_finalize<FIN, FOUT, ACT><<<igrid((long long)N * FOUT, 256), 256, 0, stream>>>(
        xin, agg, deg, root, bias, hconv, N);
    pool_init<<<igrid((long long)C * FOUT + C, 256), 256, 0, stream>>>(segw, pooled, C, C * FOUT);
    if (WEIGHTED)
        att_segmax<FOUT><<<igrid(N, 256), 256, 0, stream>>>(hconv, attw, attb, cluster, wbuf, segw, N);
    pool_scatter<FOUT, WEIGHTED><<<igrid((long long)N * FOUT, 256), 256, 0, stream>>>(
        hconv, wbuf, segw, cluster, pooled, N);
    pool_final<<<igrid((long long)C * FOUT, 256), 256, 0, stream>>>(pooled, hpool, C * FOUT);
}

extern "C" void kernel_launch(void* const* d_in, const int* in_sizes, int n_in,
                              void* d_out, int out_size, void* d_ws, size_t ws_size,
                              hipStream_t stream)
{
    const float* x0 = (const float*)d_in[0];
    const int*   src_[5]    = {(const int*)d_in[1], (const int*)d_in[4], (const int*)d_in[7], (const int*)d_in[10], (const int*)d_in[13]};
    const int*   dst_[5]    = {(const int*)d_in[2], (const int*)d_in[5], (const int*)d_in[8], (const int*)d_in[11], (const int*)d_in[14]};
    const float* ps_[5]     = {(const float*)d_in[3], (const float*)d_in[6], (const float*)d_in[9], (const float*)d_in[12], (const float*)d_in[15]};
    const int*   cl_[5]     = {(const int*)d_in[16], (const int*)d_in[17], (const int*)d_in[18], (const int*)d_in[19], (const int*)d_in[20]};
    const float* W_[5]      = {(const float*)d_in[21], (const float*)d_in[24], (const float*)d_in[27], (const float*)d_in[30], (const float*)d_in[33]};
    const float* root_[5]   = {(const float*)d_in[22], (const float*)d_in[25], (const float*)d_in[28], (const float*)d_in[31], (const float*)d_in[34]};
    const float* b_[5]      = {(const float*)d_in[23], (const float*)d_in[26], (const float*)d_in[29], (const float*)d_in[32], (const float*)d_in[35]};
    const float* attw_[4]   = {(const float*)d_in[36], (const float*)d_in[38], (const float*)d_in[40], (const float*)d_in[42]};
    const float* attb_[4]   = {(const float*)d_in[37], (const float*)d_in[39], (const float*)d_in[41], (const float*)d_in[43]};
    const float* fcw = (const float*)d_in[44];
    const float* fcb = (const float*)d_in[45];

    // workspace arena (floats): hA (conv out, max 30000*32 = 960000),
    // agg (960000), hB (pool out, max 320000 + pad), deg, wbuf, segw, pooled
    float* hA   = (float*)d_ws;
    float* agg  = hA  + 960000;
    float* hB   = agg + 960000;
    float* deg  = hB  + 330000;
    float* wbuf = deg + 30016;
    unsigned int* segw   = (unsigned int*)(wbuf + 30016);
    unsigned int* pooled = segw + 10016;   // 320000 u32

    // L0: Fin=1, Fout=32, ELU, weighted pool -> C=10000
    run_layer<1, 32, 0, true>(x0, src_[0], dst_[0], ps_[0], W_[0], root_[0], b_[0],
                              attw_[0], attb_[0], cl_[0], 30000, 360000, 10000,
                              agg, deg, wbuf, segw, pooled, hA, hB, stream);
    // L1: 32->64
    run_layer<32, 64, 0, true>(hB, src_[1], dst_[1], ps_[1], W_[1], root_[1], b_[1],
                               attw_[1], attb_[1], cl_[1], 10000, 120000, 4000,
                               agg, deg, wbuf, segw, pooled, hA, hB, stream);
    // L2: 64->64
    run_layer<64, 64, 0, true>(hB, src_[2], dst_[2], ps_[2], W_[2], root_[2], b_[2],
                               attw_[2], attb_[2], cl_[2], 4000, 48000, 1500,
                               agg, deg, wbuf, segw, pooled, hA, hB, stream);
    // L3: 64->64
    run_layer<64, 64, 0, true>(hB, src_[3], dst_[3], ps_[3], W_[3], root_[3], b_[3],
                               attw_[3], attb_[3], cl_[3], 1500, 18000, 600,
                               agg, deg, wbuf, segw, pooled, hA, hB, stream);
    // L4: 64->64, ReLU, dense pool -> C=128
    run_layer<64, 64, 1, false>(hB, src_[4], dst_[4], ps_[4], W_[4], root_[4], b_[4],
                                nullptr, nullptr, cl_[4], 600, 7200, 128,
                                agg, deg, wbuf, segw, pooled, hA, hB, stream);

    // final FC + log_softmax  ([128,64] -> [16,512] @ [512,10])
    fc_logsoftmax<<<1, 192, 0, stream>>>(hB, fcw, fcb, (float*)d_out);
}

// Round 3
// 1010.989 us; speedup vs baseline: 1.4041x; 1.4041x over previous
//
#include <hip/hip_runtime.h>
#include <math.h>

#define KS 5
#define NEGV (-1e30f)

typedef __bf16 bf16x8 __attribute__((ext_vector_type(8)));
typedef float f32x4 __attribute__((ext_vector_type(4)));

__device__ __forceinline__ unsigned int flipf(float f) {
    unsigned int b = __float_as_uint(f);
    return b ^ ((b >> 31) ? 0xFFFFFFFFu : 0x80000000u);
}
__device__ __forceinline__ float unflipf(unsigned int u) {
    unsigned int b = u ^ ((u >> 31) ? 0x80000000u : 0xFFFFFFFFu);
    return __uint_as_float(b);
}

// ctrl (ints): [0,64) hist | [64,128) cursor | [128,193) bucket_base | [200,265) chunk_prefix | [272] total_chunks

__device__ __forceinline__ void basis1(float p, int& b, float& f) {
    float v = fminf(fmaxf(p, 0.f), 1.f) * (float)(KS - 1);
    float fl = fminf(floorf(v), (float)(KS - 2));
    b = (int)fl; f = v - fl;
}

// ---------- edge prep: cell id, histogram, degree ----------
__global__ void edge_prep(const float* __restrict__ pseudo,
                          const int* __restrict__ dst,
                          int* __restrict__ cell,
                          int* __restrict__ ctrl,
                          float* __restrict__ deg, int E)
{
    __shared__ int lh[64];
    int t = threadIdx.x;
    if (t < 64) lh[t] = 0;
    __syncthreads();
    int gs = gridDim.x * blockDim.x;
    for (int e = blockIdx.x * blockDim.x + t; e < E; e += gs) {
        int b0, b1, b2; float f0, f1, f2;
        basis1(pseudo[e * 3 + 0], b0, f0);
        basis1(pseudo[e * 3 + 1], b1, f1);
        basis1(pseudo[e * 3 + 2], b2, f2);
        int c = b0 + 4 * b1 + 16 * b2;
        cell[e] = c;
        atomicAdd(&lh[c], 1);
        atomicAdd(&deg[dst[e]], 1.0f);
    }
    __syncthreads();
    if (t < 64 && lh[t]) atomicAdd(&ctrl[t], lh[t]);
}

// ---------- single-wave scan of 64 buckets ----------
__global__ void scan_ctrl(int* __restrict__ ctrl)
{
    int l = threadIdx.x;       // 64 threads = 1 wave
    int h = ctrl[l];
    int x = h;
    #pragma unroll
    for (int off = 1; off < 64; off <<= 1) { int y = __shfl_up(x, off, 64); if (l >= off) x += y; }
    int excl = x - h;
    ctrl[128 + l] = excl;      // bucket_base
    ctrl[64 + l] = excl;       // cursor
    int ch = (h + 63) >> 6;
    int cx = ch;
    #pragma unroll
    for (int off = 1; off < 64; off <<= 1) { int y = __shfl_up(cx, off, 64); if (l >= off) cx += y; }
    ctrl[200 + l] = cx - ch;   // chunk_prefix
    if (l == 63) { ctrl[128 + 64] = excl + h; ctrl[200 + 64] = cx; ctrl[272] = cx; }
}

// ---------- scatter edge ids into bucket order ----------
__global__ void edge_scatter(const int* __restrict__ cell,
                             int* __restrict__ ctrl,
                             int* __restrict__ eord, int E)
{
    int gs = gridDim.x * blockDim.x;
    for (int e = blockIdx.x * blockDim.x + threadIdx.x; e < E; e += gs) {
        int pos = atomicAdd(&ctrl[64 + cell[e]], 1);
        eord[pos] = e;
    }
}

// ---------- pack W per cell into k-packed bf16 (split-3 for exactness) ----------
template<int FIN, int FOUT, int KB, int NSPLIT>
__global__ void bpack(const float* __restrict__ W,
                      __bf16* __restrict__ BpH,
                      __bf16* __restrict__ BpM,
                      __bf16* __restrict__ BpL)
{
    int t = blockIdx.x * blockDim.x + threadIdx.x;
    if (t >= 64 * KB * FOUT) return;
    int o = t % FOUT;
    int kb = (t / FOUT) % KB;
    int cellid = t / (FOUT * KB);
    int b0 = cellid & 3, b1 = (cellid >> 2) & 3, b2 = cellid >> 4;
    bf16x8 vh, vm, vl;
    #pragma unroll
    for (int j = 0; j < 8; ++j) {
        int r = kb * 8 + j;
        float val = 0.f;
        if (r < 8 * FIN) {
            int c = r / FIN, i = r % FIN;
            int k = (b0 + (c & 1)) + 5 * (b1 + ((c >> 1) & 1)) + 25 * (b2 + (c >> 2));
            val = W[((size_t)k * FIN + i) * FOUT + o];
        }
        __bf16 hv = (__bf16)val;
        vh[j] = hv;
        if (NSPLIT == 3) {
            float r1 = val - (float)hv;
            __bf16 mv = (__bf16)r1;
            vm[j] = mv;
            vl[j] = (__bf16)(r1 - (float)mv);
        }
    }
    *reinterpret_cast<bf16x8*>(BpH + (size_t)t * 8) = vh;
    if (NSPLIT == 3) {
        *reinterpret_cast<bf16x8*>(BpM + (size_t)t * 8) = vm;
        *reinterpret_cast<bf16x8*>(BpL + (size_t)t * 8) = vl;
    }
}

// ---------- bucketed MFMA conv: 64 edges per block (4 waves x 16 rows) ----------
template<int FIN, int FOUT, int NSPLIT>
__global__ void conv_mfma(const float* __restrict__ x,
                          const int* __restrict__ src,
                          const int* __restrict__ dst,
                          const float* __restrict__ pseudo,
                          const __bf16* __restrict__ BpH,
                          const __bf16* __restrict__ BpM,
                          const __bf16* __restrict__ BpL,
                          const int* __restrict__ ctrl,
                          const int* __restrict__ eord,
                          float* __restrict__ agg)
{
    constexpr int KB = (FIN == 1) ? 4 : FIN;
    constexpr int KSTEPS = (FIN == 1) ? 1 : FIN / 4;
    constexpr int NF = FOUT / 16;

    int bid = blockIdx.x;
    if (bid >= ctrl[272]) return;
    int blo = 0, bhi = 64;
    while (blo + 1 < bhi) { int mid = (blo + bhi) >> 1; if (ctrl[200 + mid] <= bid) blo = mid; else bhi = mid; }
    int bucket = blo;
    int m0 = (bid - ctrl[200 + bucket]) << 6;
    int bbase = ctrl[128 + bucket];
    int bsize = ctrl[128 + bucket + 1] - bbase;

    int lane = threadIdx.x & 63;
    int wave = threadIdx.x >> 6;
    int h4 = lane >> 4;
    int col = lane & 15;
    int row = m0 + wave * 16 + col;
    bool valid = row < bsize;
    int e = eord[bbase + (valid ? row : 0)];
    int s = src[e];

    float bw[8];
    {
        int b0, b1, b2; float f0, f1, f2;
        basis1(pseudo[e * 3 + 0], b0, f0);
        basis1(pseudo[e * 3 + 1], b1, f1);
        basis1(pseudo[e * 3 + 2], b2, f2);
        float g0 = 1.f - f0, g1 = 1.f - f1, g2 = 1.f - f2;
        float vf = valid ? 1.f : 0.f;
        #pragma unroll
        for (int j = 0; j < 8; ++j)
            bw[j] = vf * ((j & 1) ? f0 : g0) * (((j >> 1) & 1) ? f1 : g1) * (((j >> 2) & 1) ? f2 : g2);
    }

    float4 xe0, xe1, xo0, xo1; float xsc = 0.f;
    if (FIN >= 32) {
        const float4* xb = reinterpret_cast<const float4*>(x + (size_t)s * FIN + h4 * 8);
        xe0 = xb[0]; xe1 = xb[1];
        if (FIN == 64) {
            const float4* xb2 = reinterpret_cast<const float4*>(x + (size_t)s * FIN + 32 + h4 * 8);
            xo0 = xb2[0]; xo1 = xb2[1];
        }
    } else {
        xsc = x[s];
    }

    f32x4 acc[NF];
    #pragma unroll
    for (int nf = 0; nf < NF; ++nf) acc[nf] = (f32x4){0.f, 0.f, 0.f, 0.f};

    #pragma unroll
    for (int kt = 0; kt < KSTEPS; ++kt) {
        float v[8];
        if (FIN == 64) {
            float bwc = bw[kt >> 1];
            float4 u0 = (kt & 1) ? xo0 : xe0;
            float4 u1 = (kt & 1) ? xo1 : xe1;
            v[0] = u0.x * bwc; v[1] = u0.y * bwc; v[2] = u0.z * bwc; v[3] = u0.w * bwc;
            v[4] = u1.x * bwc; v[5] = u1.y * bwc; v[6] = u1.z * bwc; v[7] = u1.w * bwc;
        } else if (FIN == 32) {
            float bwc = bw[kt];
            v[0] = xe0.x * bwc; v[1] = xe0.y * bwc; v[2] = xe0.z * bwc; v[3] = xe0.w * bwc;
            v[4] = xe1.x * bwc; v[5] = xe1.y * bwc; v[6] = xe1.z * bwc; v[7] = xe1.w * bwc;
        } else {
            float xm = (h4 == 0) ? xsc : 0.f;
            #pragma unroll
            for (int j = 0; j < 8; ++j) v[j] = bw[j] * xm;
        }
        bf16x8 ah, am, al;
        #pragma unroll
        for (int j = 0; j < 8; ++j) {
            __bf16 hv = (__bf16)v[j];
            ah[j] = hv;
            if (NSPLIT == 3) {
                float r1 = v[j] - (float)hv;
                __bf16 mv = (__bf16)r1;
                am[j] = mv;
                al[j] = (__bf16)(r1 - (float)mv);
            }
        }
        #pragma unroll
        for (int nf = 0; nf < NF; ++nf) {
            size_t boff = (((size_t)bucket * KB + (kt * 4 + h4)) * FOUT + nf * 16 + col) * 8;
            bf16x8 bh = *reinterpret_cast<const bf16x8*>(BpH + boff);
            acc[nf] = __builtin_amdgcn_mfma_f32_16x16x32_bf16(ah, bh, acc[nf], 0, 0, 0);
            if (NSPLIT == 3) {
                bf16x8 bm = *reinterpret_cast<const bf16x8*>(BpM + boff);
                bf16x8 bl = *reinterpret_cast<const bf16x8*>(BpL + boff);
                acc[nf] = __builtin_amdgcn_mfma_f32_16x16x32_bf16(ah, bm, acc[nf], 0, 0, 0);
                acc[nf] = __builtin_amdgcn_mfma_f32_16x16x32_bf16(am, bh, acc[nf], 0, 0, 0);
                acc[nf] = __builtin_amdgcn_mfma_f32_16x16x32_bf16(am, bm, acc[nf], 0, 0, 0);
                acc[nf] = __builtin_amdgcn_mfma_f32_16x16x32_bf16(ah, bl, acc[nf], 0, 0, 0);
                acc[nf] = __builtin_amdgcn_mfma_f32_16x16x32_bf16(al, bh, acc[nf], 0, 0, 0);
            }
        }
    }

    // C/D layout: col = lane&15, row = (lane>>4)*4 + j
    #pragma unroll
    for (int j = 0; j < 4; ++j) {
        int orow = m0 + wave * 16 + h4 * 4 + j;
        if (orow < bsize) {
            int eo = eord[bbase + orow];
            int d = dst[eo];
            #pragma unroll
            for (int nf = 0; nf < NF; ++nf)
                atomicAdd(&agg[(size_t)d * FOUT + nf * 16 + col], acc[nf][j]);
        }
    }
}

// ---------- finalize: mean + root + bias + act, fused attention seg-max ----------
template<int FIN, int FOUT, int ACT, bool WEIGHTED>  // ACT 0=ELU 1=ReLU
__global__ void node_finalize(const float* __restrict__ x,
                              const float* __restrict__ agg,
                              const float* __restrict__ deg,
                              const float* __restrict__ root,
                              const float* __restrict__ bias,
                              const float* __restrict__ attw,
                              const float* __restrict__ attb,
                              const int* __restrict__ cluster,
                              float* __restrict__ out,
                              float* __restrict__ wbuf,
                              unsigned int* __restrict__ segw,
                              int N)
{
    int t = blockIdx.x * blockDim.x + threadIdx.x;
    int n = t / FOUT, o = t % FOUT;
    if (n >= N) return;   // grids are exact; waves never straddle
    float a = agg[t] / fmaxf(deg[n], 1.f) + bias[o];
    #pragma unroll
    for (int i = 0; i < FIN; ++i)
        a = fmaf(x[(size_t)n * FIN + i], root[i * FOUT + o], a);
    if (ACT == 0) a = (a > 0.f) ? a : expm1f(a);
    else          a = fmaxf(a, 0.f);
    out[t] = a;
    if (WEIGHTED) {
        float w = a * attw[2 * o];
        #pragma unroll
        for (int off = FOUT / 2; off >= 1; off >>= 1)
            w += __shfl_xor(w, off, 64);
        if (o == 0) {
            float wt = w + attb[0];
            wbuf[n] = wt;
            atomicMax(&segw[cluster[n]], flipf(wt));
        }
    }
}

// ---------- pool helpers ----------
__global__ void pool_init(unsigned int* __restrict__ segw,
                          unsigned int* __restrict__ pooled, int C, int CF)
{
    int gs = gridDim.x * blockDim.x;
    unsigned int v = flipf(NEGV);
    for (int t = blockIdx.x * blockDim.x + threadIdx.x; t < C; t += gs) segw[t] = v;
    for (int t = blockIdx.x * blockDim.x + threadIdx.x; t < CF; t += gs) pooled[t] = v;
}

template<int F, bool WEIGHTED>
__global__ void pool_scatter(const float* __restrict__ x,
                             const float* __restrict__ wout,
                             const unsigned int* __restrict__ segw,
                             const int* __restrict__ cluster,
                             unsigned int* __restrict__ pooled, int N)
{
    int gs = gridDim.x * blockDim.x;
    int total = N * F;
    for (int t = blockIdx.x * blockDim.x + threadIdx.x; t < total; t += gs) {
        int n = t / F;
        int f = t - n * F;
        int c = cluster[n];
        bool win = true;
        if (WEIGHTED) win = (wout[n] >= unflipf(segw[c]));
        if (win) atomicMax(&pooled[(size_t)c * F + f], flipf(x[t]));
    }
}

__global__ void pool_final(const unsigned int* __restrict__ pooled,
                           float* __restrict__ out, int total)
{
    int gs = gridDim.x * blockDim.x;
    for (int t = blockIdx.x * blockDim.x + threadIdx.x; t < total; t += gs) {
        float v = unflipf(pooled[t]);
        out[t] = (v <= NEGV * 0.5f) ? 0.f : v;
    }
}

// ---------- final FC + log_softmax ----------
__global__ void fc_logsoftmax(const float* __restrict__ h,
                              const float* __restrict__ fcw,
                              const float* __restrict__ fcb,
                              float* __restrict__ out)
{
    __shared__ float logits[16][10];
    __shared__ float lse[16];
    int t = threadIdx.x;
    if (t < 160) {
        int g = t / 10, cls = t - g * 10;
        float a = fcb[cls];
        for (int j = 0; j < 512; ++j)
            a = fmaf(h[g * 512 + j], fcw[j * 10 + cls], a);
        logits[g][cls] = a;
    }
    __syncthreads();
    if (t < 16) {
        float m = -1e30f;
        for (int c = 0; c < 10; ++c) m = fmaxf(m, logits[t][c]);
        float s = 0.f;
        for (int c = 0; c < 10; ++c) s += expf(logits[t][c] - m);
        lse[t] = m + logf(s);
    }
    __syncthreads();
    if (t < 160) out[t] = logits[t / 10][t - (t / 10) * 10] - lse[t / 10];
}

// ---------- host ----------
static inline int igrid(long long total, int block, int cap = 2048) {
    long long g = (total + block - 1) / block;
    if (g > cap) g = cap;
    if (g < 1) g = 1;
    return (int)g;
}

// ws float offsets
#define OFF_HA     0
#define OFF_HB     960000
#define OFF_AGG    1290000
#define OFF_DEG    2250000
#define OFF_WBUF   2280016
#define OFF_SEGW   2310032
#define OFF_POOLED 2320048
#define OFF_CTRL   2640048
#define OFF_CELL   2640560
#define OFF_EORD   3000560
#define OFF_BP     3360560
#define BP_PLANE   2097152   // bf16 elems per split plane

template<int FIN, int FOUT, int ACT, bool WEIGHTED, int NSPLIT>
static void run_layer(const float* xin,
                      const int* src, const int* dst, const float* ps,
                      const float* W, const float* root, const float* bias,
                      const float* attw, const float* attb, const int* cluster,
                      int N, int E, int C,
                      float* ws_f, float* hout_pool, hipStream_t stream)
{
    constexpr int KB = (FIN == 1) ? 4 : FIN;
    float* hA = ws_f + OFF_HA;
    float* agg = ws_f + OFF_AGG;
    float* deg = ws_f + OFF_DEG;
    float* wbuf = ws_f + OFF_WBUF;
    unsigned int* segw = (unsigned int*)(ws_f + OFF_SEGW);
    unsigned int* pooled = (unsigned int*)(ws_f + OFF_POOLED);
    int* ctrl = (int*)(ws_f + OFF_CTRL);
    int* cell = (int*)(ws_f + OFF_CELL);
    int* eord = (int*)(ws_f + OFF_EORD);
    __bf16* BpH = (__bf16*)(ws_f + OFF_BP);
    __bf16* BpM = BpH + BP_PLANE;
    __bf16* BpL = BpM + BP_PLANE;

    // one memset covers agg, deg, wbuf, segw, pooled, ctrl (all re-initialized per layer)
    hipMemsetAsync(agg, 0, (size_t)(OFF_CTRL + 512 - OFF_AGG) * 4, stream);
    // pool_init MUST precede node_finalize (which atomicMaxes segw)
    pool_init<<<igrid((long long)C * FOUT + C, 256), 256, 0, stream>>>(segw, pooled, C, C * FOUT);
    edge_prep<<<igrid(E, 256), 256, 0, stream>>>(ps, dst, cell, ctrl, deg, E);
    scan_ctrl<<<1, 64, 0, stream>>>(ctrl);
    edge_scatter<<<igrid(E, 256), 256, 0, stream>>>(cell, ctrl, eord, E);
    int bt = 64 * KB * FOUT;
    bpack<FIN, FOUT, KB, NSPLIT><<<(bt + 255) / 256, 256, 0, stream>>>(W, BpH, BpM, BpL);
    conv_mfma<FIN, FOUT, NSPLIT><<<E / 64 + 65, 256, 0, stream>>>(
        xin, src, dst, ps, BpH, BpM, BpL, ctrl, eord, agg);
    node_finalize<FIN, FOUT, ACT, WEIGHTED><<<(N * FOUT) / 256, 256, 0, stream>>>(
        xin, agg, deg, root, bias, attw, attb, cluster, hA, wbuf, segw, N);
    pool_scatter<FOUT, WEIGHTED><<<igrid((long long)N * FOUT, 256), 256, 0, stream>>>(
        hA, wbuf, segw, cluster, pooled, N);
    pool_final<<<igrid((long long)C * FOUT, 256), 256, 0, stream>>>(pooled, hout_pool, C * FOUT);
}

extern "C" void kernel_launch(void* const* d_in, const int* in_sizes, int n_in,
                              void* d_out, int out_size, void* d_ws, size_t ws_size,
                              hipStream_t stream)
{
    const float* x0 = (const float*)d_in[0];
    const int*   src_[5]  = {(const int*)d_in[1], (const int*)d_in[4], (const int*)d_in[7], (const int*)d_in[10], (const int*)d_in[13]};
    const int*   dst_[5]  = {(const int*)d_in[2], (const int*)d_in[5], (const int*)d_in[8], (const int*)d_in[11], (const int*)d_in[14]};
    const float* ps_[5]   = {(const float*)d_in[3], (const float*)d_in[6], (const float*)d_in[9], (const float*)d_in[12], (const float*)d_in[15]};
    const int*   cl_[5]   = {(const int*)d_in[16], (const int*)d_in[17], (const int*)d_in[18], (const int*)d_in[19], (const int*)d_in[20]};
    const float* W_[5]    = {(const float*)d_in[21], (const float*)d_in[24], (const float*)d_in[27], (const float*)d_in[30], (const float*)d_in[33]};
    const float* root_[5] = {(const float*)d_in[22], (const float*)d_in[25], (const float*)d_in[28], (const float*)d_in[31], (const float*)d_in[34]};
    const float* b_[5]    = {(const float*)d_in[23], (const float*)d_in[26], (const float*)d_in[29], (const float*)d_in[32], (const float*)d_in[35]};
    const float* attw_[4] = {(const float*)d_in[36], (const float*)d_in[38], (const float*)d_in[40], (const float*)d_in[42]};
    const float* attb_[4] = {(const float*)d_in[37], (const float*)d_in[39], (const float*)d_in[41], (const float*)d_in[43]};
    const float* fcw = (const float*)d_in[44];
    const float* fcb = (const float*)d_in[45];

    float* ws_f = (float*)d_ws;
    float* hB = ws_f + OFF_HB;

    run_layer<1, 32, 0, true, 3>(x0, src_[0], dst_[0], ps_[0], W_[0], root_[0], b_[0],
                                 attw_[0], attb_[0], cl_[0], 30000, 360000, 10000,
                                 ws_f, hB, stream);
    run_layer<32, 64, 0, true, 3>(hB, src_[1], dst_[1], ps_[1], W_[1], root_[1], b_[1],
                                  attw_[1], attb_[1], cl_[1], 10000, 120000, 4000,
                                  ws_f, hB, stream);
    run_layer<64, 64, 0, true, 3>(hB, src_[2], dst_[2], ps_[2], W_[2], root_[2], b_[2],
                                  attw_[2], attb_[2], cl_[2], 4000, 48000, 1500,
                                  ws_f, hB, stream);
    run_layer<64, 64, 0, true, 3>(hB, src_[3], dst_[3], ps_[3], W_[3], root_[3], b_[3],
                                  attw_[3], attb_[3], cl_[3], 1500, 18000, 600,
                                  ws_f, hB, stream);
    run_layer<64, 64, 1, false, 3>(hB, src_[4], dst_[4], ps_[4], W_[4], root_[4], b_[4],
                                   nullptr, nullptr, cl_[4], 600, 7200, 128,
                                   ws_f, hB, stream);

    fc_logsoftmax<<<1, 192, 0, stream>>>(hB, fcw, fcb, (float*)d_out);
}

// Round 4
// 402.854 us; speedup vs baseline: 3.5238x; 2.5096x over previous
//
#include <hip/hip_runtime.h>
#include <math.h>

#define KS 5
#define NEGV (-1e30f)

typedef __bf16 bf16x8 __attribute__((ext_vector_type(8)));
typedef float f32x4 __attribute__((ext_vector_type(4)));

__device__ __forceinline__ unsigned int flipf(float f) {
    unsigned int b = __float_as_uint(f);
    return b ^ ((b >> 31) ? 0xFFFFFFFFu : 0x80000000u);
}
__device__ __forceinline__ float unflipf(unsigned int u) {
    unsigned int b = u ^ ((u >> 31) ? 0x80000000u : 0xFFFFFFFFu);
    return __uint_as_float(b);
}

// ctrl (ints): [0,64) hist | [64,128) unused | [128,193) bucket_base | [200,265) chunk_prefix | [272] total_chunks

__device__ __forceinline__ void basis1(float p, int& b, float& f) {
    float v = fminf(fmaxf(p, 0.f), 1.f) * (float)(KS - 1);
    float fl = fminf(floorf(v), (float)(KS - 2));
    b = (int)fl; f = v - fl;
}

// ---------- edge prep: cell id, per-block histogram -> per-block base, degree ----------
__global__ void edge_prep(const float* __restrict__ pseudo,
                          const int* __restrict__ dst,
                          int* __restrict__ cell,
                          int* __restrict__ ctrl,
                          int* __restrict__ blkbase,
                          float* __restrict__ deg, int E)
{
    __shared__ int lh[64];
    int t = threadIdx.x;
    if (t < 64) lh[t] = 0;
    __syncthreads();
    int gs = gridDim.x * blockDim.x;
    for (int e = blockIdx.x * blockDim.x + t; e < E; e += gs) {
        int b0, b1, b2; float f0, f1, f2;
        basis1(pseudo[e * 3 + 0], b0, f0);
        basis1(pseudo[e * 3 + 1], b1, f1);
        basis1(pseudo[e * 3 + 2], b2, f2);
        int c = b0 + 4 * b1 + 16 * b2;
        cell[e] = c;
        atomicAdd(&lh[c], 1);
        atomicAdd(&deg[dst[e]], 1.0f);
    }
    __syncthreads();
    // old value of running bucket total = this block's base within the bucket
    if (t < 64) blkbase[blockIdx.x * 64 + t] = atomicAdd(&ctrl[t], lh[t]);
}

// ---------- single-wave scan of 64 buckets ----------
__global__ void scan_ctrl(int* __restrict__ ctrl)
{
    int l = threadIdx.x;       // 64 threads = 1 wave
    int h = ctrl[l];
    int x = h;
    #pragma unroll
    for (int off = 1; off < 64; off <<= 1) { int y = __shfl_up(x, off, 64); if (l >= off) x += y; }
    int excl = x - h;
    ctrl[128 + l] = excl;      // bucket_base
    int ch = (h + 63) >> 6;
    int cx = ch;
    #pragma unroll
    for (int off = 1; off < 64; off <<= 1) { int y = __shfl_up(cx, off, 64); if (l >= off) cx += y; }
    ctrl[200 + l] = cx - ch;   // chunk_prefix
    if (l == 63) { ctrl[128 + 64] = excl + h; ctrl[200 + 64] = cx; ctrl[272] = cx; }
}

// ---------- scatter edge ids into bucket order (LDS cursors, no global contention) ----------
__global__ void edge_scatter(const int* __restrict__ cell,
                             const int* __restrict__ ctrl,
                             const int* __restrict__ blkbase,
                             int* __restrict__ eord, int E)
{
    __shared__ int cur[64];
    int t = threadIdx.x;
    if (t < 64) cur[t] = ctrl[128 + t] + blkbase[blockIdx.x * 64 + t];
    __syncthreads();
    int gs = gridDim.x * blockDim.x;
    for (int e = blockIdx.x * blockDim.x + t; e < E; e += gs) {
        int pos = atomicAdd(&cur[cell[e]], 1);
        eord[pos] = e;
    }
}

// ---------- pack W per cell into k-packed bf16 (split-3 for exactness) ----------
template<int FIN, int FOUT, int KB, int NSPLIT>
__global__ void bpack(const float* __restrict__ W,
                      __bf16* __restrict__ BpH,
                      __bf16* __restrict__ BpM,
                      __bf16* __restrict__ BpL)
{
    int t = blockIdx.x * blockDim.x + threadIdx.x;
    if (t >= 64 * KB * FOUT) return;
    int o = t % FOUT;
    int kb = (t / FOUT) % KB;
    int cellid = t / (FOUT * KB);
    int b0 = cellid & 3, b1 = (cellid >> 2) & 3, b2 = cellid >> 4;
    bf16x8 vh, vm, vl;
    #pragma unroll
    for (int j = 0; j < 8; ++j) {
        int r = kb * 8 + j;
        float val = 0.f;
        if (r < 8 * FIN) {
            int c = r / FIN, i = r % FIN;
            int k = (b0 + (c & 1)) + 5 * (b1 + ((c >> 1) & 1)) + 25 * (b2 + (c >> 2));
            val = W[((size_t)k * FIN + i) * FOUT + o];
        }
        __bf16 hv = (__bf16)val;
        vh[j] = hv;
        if (NSPLIT == 3) {
            float r1 = val - (float)hv;
            __bf16 mv = (__bf16)r1;
            vm[j] = mv;
            vl[j] = (__bf16)(r1 - (float)mv);
        }
    }
    *reinterpret_cast<bf16x8*>(BpH + (size_t)t * 8) = vh;
    if (NSPLIT == 3) {
        *reinterpret_cast<bf16x8*>(BpM + (size_t)t * 8) = vm;
        *reinterpret_cast<bf16x8*>(BpL + (size_t)t * 8) = vl;
    }
}

// ---------- bucketed MFMA conv: 64 edges per block (4 waves x 16 rows) ----------
template<int FIN, int FOUT, int NSPLIT>
__global__ void conv_mfma(const float* __restrict__ x,
                          const int* __restrict__ src,
                          const int* __restrict__ dst,
                          const float* __restrict__ pseudo,
                          const __bf16* __restrict__ BpH,
                          const __bf16* __restrict__ BpM,
                          const __bf16* __restrict__ BpL,
                          const int* __restrict__ ctrl,
                          const int* __restrict__ eord,
                          float* __restrict__ agg)
{
    constexpr int KB = (FIN == 1) ? 4 : FIN;
    constexpr int KSTEPS = (FIN == 1) ? 1 : FIN / 4;
    constexpr int NF = FOUT / 16;

    int bid = blockIdx.x;
    if (bid >= ctrl[272]) return;
    int blo = 0, bhi = 64;
    while (blo + 1 < bhi) { int mid = (blo + bhi) >> 1; if (ctrl[200 + mid] <= bid) blo = mid; else bhi = mid; }
    int bucket = blo;
    int m0 = (bid - ctrl[200 + bucket]) << 6;
    int bbase = ctrl[128 + bucket];
    int bsize = ctrl[128 + bucket + 1] - bbase;

    int lane = threadIdx.x & 63;
    int wave = threadIdx.x >> 6;
    int h4 = lane >> 4;
    int col = lane & 15;
    int row = m0 + wave * 16 + col;
    bool valid = row < bsize;
    int e = eord[bbase + (valid ? row : 0)];
    int s = src[e];

    float bw[8];
    {
        int b0, b1, b2; float f0, f1, f2;
        basis1(pseudo[e * 3 + 0], b0, f0);
        basis1(pseudo[e * 3 + 1], b1, f1);
        basis1(pseudo[e * 3 + 2], b2, f2);
        float g0 = 1.f - f0, g1 = 1.f - f1, g2 = 1.f - f2;
        float vf = valid ? 1.f : 0.f;
        #pragma unroll
        for (int j = 0; j < 8; ++j)
            bw[j] = vf * ((j & 1) ? f0 : g0) * (((j >> 1) & 1) ? f1 : g1) * (((j >> 2) & 1) ? f2 : g2);
    }

    float4 xe0, xe1, xo0, xo1; float xsc = 0.f;
    if (FIN >= 32) {
        const float4* xb = reinterpret_cast<const float4*>(x + (size_t)s * FIN + h4 * 8);
        xe0 = xb[0]; xe1 = xb[1];
        if (FIN == 64) {
            const float4* xb2 = reinterpret_cast<const float4*>(x + (size_t)s * FIN + 32 + h4 * 8);
            xo0 = xb2[0]; xo1 = xb2[1];
        }
    } else {
        xsc = x[s];
    }

    f32x4 acc[NF];
    #pragma unroll
    for (int nf = 0; nf < NF; ++nf) acc[nf] = (f32x4){0.f, 0.f, 0.f, 0.f};

    #pragma unroll
    for (int kt = 0; kt < KSTEPS; ++kt) {
        float v[8];
        if (FIN == 64) {
            float bwc = bw[kt >> 1];
            float4 u0 = (kt & 1) ? xo0 : xe0;
            float4 u1 = (kt & 1) ? xo1 : xe1;
            v[0] = u0.x * bwc; v[1] = u0.y * bwc; v[2] = u0.z * bwc; v[3] = u0.w * bwc;
            v[4] = u1.x * bwc; v[5] = u1.y * bwc; v[6] = u1.z * bwc; v[7] = u1.w * bwc;
        } else if (FIN == 32) {
            float bwc = bw[kt];
            v[0] = xe0.x * bwc; v[1] = xe0.y * bwc; v[2] = xe0.z * bwc; v[3] = xe0.w * bwc;
            v[4] = xe1.x * bwc; v[5] = xe1.y * bwc; v[6] = xe1.z * bwc; v[7] = xe1.w * bwc;
        } else {
            float xm = (h4 == 0) ? xsc : 0.f;
            #pragma unroll
            for (int j = 0; j < 8; ++j) v[j] = bw[j] * xm;
        }
        bf16x8 ah, am, al;
        #pragma unroll
        for (int j = 0; j < 8; ++j) {
            __bf16 hv = (__bf16)v[j];
            ah[j] = hv;
            if (NSPLIT == 3) {
                float r1 = v[j] - (float)hv;
                __bf16 mv = (__bf16)r1;
                am[j] = mv;
                al[j] = (__bf16)(r1 - (float)mv);
            }
        }
        #pragma unroll
        for (int nf = 0; nf < NF; ++nf) {
            size_t boff = (((size_t)bucket * KB + (kt * 4 + h4)) * FOUT + nf * 16 + col) * 8;
            bf16x8 bh = *reinterpret_cast<const bf16x8*>(BpH + boff);
            acc[nf] = __builtin_amdgcn_mfma_f32_16x16x32_bf16(ah, bh, acc[nf], 0, 0, 0);
            if (NSPLIT == 3) {
                bf16x8 bm = *reinterpret_cast<const bf16x8*>(BpM + boff);
                bf16x8 bl = *reinterpret_cast<const bf16x8*>(BpL + boff);
                acc[nf] = __builtin_amdgcn_mfma_f32_16x16x32_bf16(ah, bm, acc[nf], 0, 0, 0);
                acc[nf] = __builtin_amdgcn_mfma_f32_16x16x32_bf16(am, bh, acc[nf], 0, 0, 0);
                acc[nf] = __builtin_amdgcn_mfma_f32_16x16x32_bf16(am, bm, acc[nf], 0, 0, 0);
                acc[nf] = __builtin_amdgcn_mfma_f32_16x16x32_bf16(ah, bl, acc[nf], 0, 0, 0);
                acc[nf] = __builtin_amdgcn_mfma_f32_16x16x32_bf16(al, bh, acc[nf], 0, 0, 0);
            }
        }
    }

    // C/D layout: col = lane&15, row = (lane>>4)*4 + j
    #pragma unroll
    for (int j = 0; j < 4; ++j) {
        int orow = m0 + wave * 16 + h4 * 4 + j;
        if (orow < bsize) {
            int eo = eord[bbase + orow];
            int d = dst[eo];
            #pragma unroll
            for (int nf = 0; nf < NF; ++nf)
                atomicAdd(&agg[(size_t)d * FOUT + nf * 16 + col], acc[nf][j]);
        }
    }
}

// ---------- finalize: mean + root + bias + act, fused attention seg-max ----------
template<int FIN, int FOUT, int ACT, bool WEIGHTED>  // ACT 0=ELU 1=ReLU
__global__ void node_finalize(const float* __restrict__ x,
                              const float* __restrict__ agg,
                              const float* __restrict__ deg,
                              const float* __restrict__ root,
                              const float* __restrict__ bias,
                              const float* __restrict__ attw,
                              const float* __restrict__ attb,
                              const int* __restrict__ cluster,
                              float* __restrict__ out,
                              float* __restrict__ wbuf,
                              unsigned int* __restrict__ segw,
                              int N)
{
    int t = blockIdx.x * blockDim.x + threadIdx.x;
    int n = t / FOUT, o = t % FOUT;
    if (n >= N) return;   // grids are exact; waves never straddle
    float a = agg[t] / fmaxf(deg[n], 1.f) + bias[o];
    #pragma unroll
    for (int i = 0; i < FIN; ++i)
        a = fmaf(x[(size_t)n * FIN + i], root[i * FOUT + o], a);
    if (ACT == 0) a = (a > 0.f) ? a : expm1f(a);
    else          a = fmaxf(a, 0.f);
    out[t] = a;
    if (WEIGHTED) {
        float w = a * attw[2 * o];
        #pragma unroll
        for (int off = FOUT / 2; off >= 1; off >>= 1)
            w += __shfl_xor(w, off, 64);
        if (o == 0) {
            float wt = w + attb[0];
            wbuf[n] = wt;
            atomicMax(&segw[cluster[n]], flipf(wt));
        }
    }
}

// ---------- pool helpers ----------
__global__ void pool_init(unsigned int* __restrict__ segw,
                          unsigned int* __restrict__ pooled, int C, int CF)
{
    int gs = gridDim.x * blockDim.x;
    unsigned int v = flipf(NEGV);
    for (int t = blockIdx.x * blockDim.x + threadIdx.x; t < C; t += gs) segw[t] = v;
    for (int t = blockIdx.x * blockDim.x + threadIdx.x; t < CF; t += gs) pooled[t] = v;
}

template<int F, bool WEIGHTED>
__global__ void pool_scatter(const float* __restrict__ x,
                             const float* __restrict__ wout,
                             const unsigned int* __restrict__ segw,
                             const int* __restrict__ cluster,
                             unsigned int* __restrict__ pooled, int N)
{
    int gs = gridDim.x * blockDim.x;
    int total = N * F;
    for (int t = blockIdx.x * blockDim.x + threadIdx.x; t < total; t += gs) {
        int n = t / F;
        int f = t - n * F;
        int c = cluster[n];
        bool win = true;
        if (WEIGHTED) win = (wout[n] >= unflipf(segw[c]));
        if (win) atomicMax(&pooled[(size_t)c * F + f], flipf(x[t]));
    }
}

__global__ void pool_final(const unsigned int* __restrict__ pooled,
                           float* __restrict__ out, int total)
{
    int gs = gridDim.x * blockDim.x;
    for (int t = blockIdx.x * blockDim.x + threadIdx.x; t < total; t += gs) {
        float v = unflipf(pooled[t]);
        out[t] = (v <= NEGV * 0.5f) ? 0.f : v;
    }
}

// ---------- final FC + log_softmax ----------
__global__ void fc_logsoftmax(const float* __restrict__ h,
                              const float* __restrict__ fcw,
                              const float* __restrict__ fcb,
                              float* __restrict__ out)
{
    __shared__ float logits[16][10];
    __shared__ float lse[16];
    int t = threadIdx.x;
    if (t < 160) {
        int g = t / 10, cls = t - g * 10;
        float a = fcb[cls];
        for (int j = 0; j < 512; ++j)
            a = fmaf(h[g * 512 + j], fcw[j * 10 + cls], a);
        logits[g][cls] = a;
    }
    __syncthreads();
    if (t < 16) {
        float m = -1e30f;
        for (int c = 0; c < 10; ++c) m = fmaxf(m, logits[t][c]);
        float s = 0.f;
        for (int c = 0; c < 10; ++c) s += expf(logits[t][c] - m);
        lse[t] = m + logf(s);
    }
    __syncthreads();
    if (t < 160) out[t] = logits[t / 10][t - (t / 10) * 10] - lse[t / 10];
}

// ---------- host ----------
static inline int igrid(long long total, int block, int cap = 2048) {
    long long g = (total + block - 1) / block;
    if (g > cap) g = cap;
    if (g < 1) g = 1;
    return (int)g;
}

// ws float offsets
#define OFF_HA     0
#define OFF_HB     960000
#define OFF_AGG    1290000
#define OFF_DEG    2250000
#define OFF_WBUF   2280016
#define OFF_SEGW   2310032
#define OFF_POOLED 2320048   // 320000 u32; doubles as blkbase (<=32768 ints) before pool_init
#define OFF_CTRL   2640048
#define OFF_CELL   2640560
#define OFF_EORD   3000560
#define OFF_BP     3360560
#define BP_PLANE   2097152   // bf16 elems per split plane

template<int FIN, int FOUT, int ACT, bool WEIGHTED, int NSPLIT>
static void run_layer(const float* xin,
                      const int* src, const int* dst, const float* ps,
                      const float* W, const float* root, const float* bias,
                      const float* attw, const float* attb, const int* cluster,
                      int N, int E, int C,
                      float* ws_f, float* hout_pool, hipStream_t stream)
{
    constexpr int KB = (FIN == 1) ? 4 : FIN;
    float* hA = ws_f + OFF_HA;
    float* agg = ws_f + OFF_AGG;
    float* deg = ws_f + OFF_DEG;
    float* wbuf = ws_f + OFF_WBUF;
    unsigned int* segw = (unsigned int*)(ws_f + OFF_SEGW);
    unsigned int* pooled = (unsigned int*)(ws_f + OFF_POOLED);
    int* blkbase = (int*)(ws_f + OFF_POOLED);   // alias: consumed before pool_init
    int* ctrl = (int*)(ws_f + OFF_CTRL);
    int* cell = (int*)(ws_f + OFF_CELL);
    int* eord = (int*)(ws_f + OFF_EORD);
    __bf16* BpH = (__bf16*)(ws_f + OFF_BP);
    __bf16* BpM = BpH + BP_PLANE;
    __bf16* BpL = BpM + BP_PLANE;

    int nb = igrid(E, 256, 512);   // shared fixed grid for prep/scatter

    // memset covers agg, deg, wbuf, segw, ctrl (hist)
    hipMemsetAsync(agg, 0, (size_t)(OFF_CTRL + 512 - OFF_AGG) * 4, stream);
    edge_prep<<<nb, 256, 0, stream>>>(ps, dst, cell, ctrl, blkbase, deg, E);
    scan_ctrl<<<1, 64, 0, stream>>>(ctrl);
    edge_scatter<<<nb, 256, 0, stream>>>(cell, ctrl, blkbase, eord, E);
    int bt = 64 * KB * FOUT;
    bpack<FIN, FOUT, KB, NSPLIT><<<(bt + 255) / 256, 256, 0, stream>>>(W, BpH, BpM, BpL);
    conv_mfma<FIN, FOUT, NSPLIT><<<E / 64 + 65, 256, 0, stream>>>(
        xin, src, dst, ps, BpH, BpM, BpL, ctrl, eord, agg);
    // pool_init AFTER blkbase use (aliases pooled), BEFORE node_finalize (which maxes segw)
    pool_init<<<igrid((long long)C * FOUT + C, 256), 256, 0, stream>>>(segw, pooled, C, C * FOUT);
    node_finalize<FIN, FOUT, ACT, WEIGHTED><<<(N * FOUT) / 256, 256, 0, stream>>>(
        xin, agg, deg, root, bias, attw, attb, cluster, hA, wbuf, segw, N);
    pool_scatter<FOUT, WEIGHTED><<<igrid((long long)N * FOUT, 256), 256, 0, stream>>>(
        hA, wbuf, segw, cluster, pooled, N);
    pool_final<<<igrid((long long)C * FOUT, 256), 256, 0, stream>>>(pooled, hout_pool, C * FOUT);
}

extern "C" void kernel_launch(void* const* d_in, const int* in_sizes, int n_in,
                              void* d_out, int out_size, void* d_ws, size_t ws_size,
                              hipStream_t stream)
{
    const float* x0 = (const float*)d_in[0];
    const int*   src_[5]  = {(const int*)d_in[1], (const int*)d_in[4], (const int*)d_in[7], (const int*)d_in[10], (const int*)d_in[13]};
    const int*   dst_[5]  = {(const int*)d_in[2], (const int*)d_in[5], (const int*)d_in[8], (const int*)d_in[11], (const int*)d_in[14]};
    const float* ps_[5]   = {(const float*)d_in[3], (const float*)d_in[6], (const float*)d_in[9], (const float*)d_in[12], (const float*)d_in[15]};
    const int*   cl_[5]   = {(const int*)d_in[16], (const int*)d_in[17], (const int*)d_in[18], (const int*)d_in[19], (const int*)d_in[20]};
    const float* W_[5]    = {(const float*)d_in[21], (const float*)d_in[24], (const float*)d_in[27], (const float*)d_in[30], (const float*)d_in[33]};
    const float* root_[5] = {(const float*)d_in[22], (const float*)d_in[25], (const float*)d_in[28], (const float*)d_in[31], (const float*)d_in[34]};
    const float* b_[5]    = {(const float*)d_in[23], (const float*)d_in[26], (const float*)d_in[29], (const float*)d_in[32], (const float*)d_in[35]};
    const float* attw_[4] = {(const float*)d_in[36], (const float*)d_in[38], (const float*)d_in[40], (const float*)d_in[42]};
    const float* attb_[4] = {(const float*)d_in[37], (const float*)d_in[39], (const float*)d_in[41], (const float*)d_in[43]};
    const float* fcw = (const float*)d_in[44];
    const float* fcb = (const float*)d_in[45];

    float* ws_f = (float*)d_ws;
    float* hB = ws_f + OFF_HB;

    run_layer<1, 32, 0, true, 3>(x0, src_[0], dst_[0], ps_[0], W_[0], root_[0], b_[0],
                                 attw_[0], attb_[0], cl_[0], 30000, 360000, 10000,
                                 ws_f, hB, stream);
    run_layer<32, 64, 0, true, 3>(hB, src_[1], dst_[1], ps_[1], W_[1], root_[1], b_[1],
                                  attw_[1], attb_[1], cl_[1], 10000, 120000, 4000,
                                  ws_f, hB, stream);
    run_layer<64, 64, 0, true, 3>(hB, src_[2], dst_[2], ps_[2], W_[2], root_[2], b_[2],
                                  attw_[2], attb_[2], cl_[2], 4000, 48000, 1500,
                                  ws_f, hB, stream);
    run_layer<64, 64, 0, true, 3>(hB, src_[3], dst_[3], ps_[3], W_[3], root_[3], b_[3],
                                  attw_[3], attb_[3], cl_[3], 1500, 18000, 600,
                                  ws_f, hB, stream);
    run_layer<64, 64, 1, false, 3>(hB, src_[4], dst_[4], ps_[4], W_[4], root_[4], b_[4],
                                   nullptr, nullptr, cl_[4], 600, 7200, 128,
                                   ws_f, hB, stream);

    fc_logsoftmax<<<1, 192, 0, stream>>>(hB, fcw, fcb, (float*)d_out);
}